// Round 3
// baseline (115.228 us; speedup 1.0000x reference)
//
#include <hip/hip_runtime.h>
#include <math.h>

#define BB 4
#define NN 2048
#define FF 128
#define HH 4
#define DD 32
#define NEG_SLOPE 0.2f
#define LOG2E 1.4426950408889634f

typedef __attribute__((ext_vector_type(8))) short short8;
typedef __attribute__((ext_vector_type(4))) float floatx4;
typedef __attribute__((ext_vector_type(2))) float floatx2;

__device__ __forceinline__ float exp2_fast(float x) {
#if __has_builtin(__builtin_amdgcn_exp2f)
    return __builtin_amdgcn_exp2f(x);
#else
    return exp2f(x);
#endif
}

__device__ __forceinline__ int bit_mask(unsigned int w, int bit) {
#if __has_builtin(__builtin_amdgcn_sbfe)
    return __builtin_amdgcn_sbfe((int)w, bit, 1);    // v_bfe_i32: 0 or -1
#else
    return ((int)(w << (31 - bit))) >> 31;
#endif
}

// pack two fp32 -> one u32 holding (bf16(hi)<<16 | bf16(lo)), RTNE
__device__ __forceinline__ unsigned int pack2_rtne(float lo, float hi) {
    unsigned int ul = __float_as_uint(lo); ul += 0x7FFFu + ((ul >> 16) & 1u);
    unsigned int uh = __float_as_uint(hi); uh += 0x7FFFu + ((uh >> 16) & 1u);
    return (ul >> 16) | (uh & 0xFFFF0000u);
}

// ---------------- K1: prep = {MFMA gemm_fused (blocks 0..511), pack_adj (512..1023)}
// (unchanged from verified baseline)
__global__ __launch_bounds__(256) void k_prep(const float* __restrict__ x,
                                              const float* __restrict__ W,
                                              const float* __restrict__ a_src,
                                              const float* __restrict__ a_dst,
                                              const int* __restrict__ adj,
                                              unsigned short* __restrict__ ht,
                                              float* __restrict__ es_t,
                                              float* __restrict__ ed_t,
                                              unsigned int* __restrict__ bits) {
    __shared__ unsigned short wbf[128][144];   // 36.9 KB, W as bf16 [o][i]
    __shared__ unsigned short hbf[128][24];    // 6 KB, h^T as bf16 [o][m_local]
    __shared__ float vs_s[HH][FF], vd_s[HH][FF];   // 4 KB
    __shared__ float as_s[FF], ad_s[FF];           // 1 KB
    int t = threadIdx.x;

    if (blockIdx.x >= 512) {
        // ---- pack_adj ----
        int idx = (blockIdx.x - 512) * 256 + t;
        int n = idx >> 6, w = idx & 63;
        const int4* base = (const int4*)(adj + (size_t)n * NN + w * 32);
        unsigned int word = 0;
#pragma unroll
        for (int q = 0; q < 8; ++q) {
            int4 a = base[q];
            word |= ((unsigned int)(a.x & 1)) << (q * 4 + 0);
            word |= ((unsigned int)(a.y & 1)) << (q * 4 + 1);
            word |= ((unsigned int)(a.z & 1)) << (q * 4 + 2);
            word |= ((unsigned int)(a.w & 1)) << (q * 4 + 3);
        }
        bits[idx] = word;
        return;
    }

    int m0g = blockIdx.x * 16;
    int b = m0g >> 11;
    int m_block = m0g & 2047;

    if (t < FF) { as_s[t] = a_src[t]; ad_s[t] = a_dst[t]; }
    // stage W -> bf16 LDS: 2048 chunks of 8 shorts
#pragma unroll
    for (int k = 0; k < 8; ++k) {
        int idx = t + k * 256;
        int row = idx >> 4, ch = idx & 15;           // 16 chunks of 8 per row
        const float* wp = W + (size_t)row * FF + ch * 8;
        float4 v0 = *(const float4*)wp;
        float4 v1 = *(const float4*)(wp + 4);
        unsigned int u[4];
        u[0] = pack2_rtne(v0.x, v0.y); u[1] = pack2_rtne(v0.z, v0.w);
        u[2] = pack2_rtne(v1.x, v1.y); u[3] = pack2_rtne(v1.z, v1.w);
        *(int4*)&wbf[row][ch * 8] = *(const int4*)u;
    }
    __syncthreads();

    // per-head column sums: vs[h][i] = sum_d W[h*32+d][i]*a_src[h][d]
    {
        int i = t & 127;
        float acc4[4] = {0.f, 0.f, 0.f, 0.f};
        if (t < 128) {
            for (int o = 0; o < 128; ++o) {
                float wv = __uint_as_float(((unsigned int)wbf[o][i]) << 16);
                acc4[o >> 5] += wv * as_s[o];
            }
#pragma unroll
            for (int hd = 0; hd < 4; ++hd) vs_s[hd][i] = acc4[hd];
        } else {
            for (int o = 0; o < 128; ++o) {
                float wv = __uint_as_float(((unsigned int)wbf[o][i]) << 16);
                acc4[o >> 5] += wv * ad_s[o];
            }
#pragma unroll
            for (int hd = 0; hd < 4; ++hd) vd_s[hd][i] = acc4[hd];
        }
    }

    // MFMA: h[m0g..+15][0..127] ; wave wid does col-tiles c=wid*2, wid*2+1
    int wid = t >> 6, lane = t & 63;
    int r = lane & 15, q = lane >> 4;
    floatx4 acc[2] = {{0.f,0.f,0.f,0.f},{0.f,0.f,0.f,0.f}};
    const float* xrow = x + (size_t)(m0g + r) * FF + q * 8;
#pragma unroll
    for (int kk = 0; kk < 4; ++kk) {
        float4 a0 = *(const float4*)(xrow + kk * 32);
        float4 a1 = *(const float4*)(xrow + kk * 32 + 4);
        union { short8 s8; unsigned int u[4]; } af;
        af.u[0] = pack2_rtne(a0.x, a0.y); af.u[1] = pack2_rtne(a0.z, a0.w);
        af.u[2] = pack2_rtne(a1.x, a1.y); af.u[3] = pack2_rtne(a1.z, a1.w);
#pragma unroll
        for (int c = 0; c < 2; ++c) {
            int o = (wid * 2 + c) * 16 + r;          // B col = lane&15
            short8 bf = *(const short8*)&wbf[o][kk * 32 + q * 8];
            acc[c] = __builtin_amdgcn_mfma_f32_16x16x32_bf16(af.s8, bf, acc[c], 0, 0, 0);
        }
    }
    // store h^T (bf16) to LDS: lane holds col o, rows q*4+reg
#pragma unroll
    for (int c = 0; c < 2; ++c) {
        int o = (wid * 2 + c) * 16 + r;
        unsigned int u2[2];
        u2[0] = pack2_rtne(acc[c][0], acc[c][1]);
        u2[1] = pack2_rtne(acc[c][2], acc[c][3]);
        *(int2*)&hbf[o][q * 4] = *(const int2*)u2;
    }
    __syncthreads();

    // ht write: thread t<128 handles col o=t -> ht[b*4+hd][d][m_block..+15]
    if (t < 128) {
        int hd = t >> 5, d = t & 31;
        unsigned short* op = ht + ((size_t)(b * HH + hd) * DD + d) * NN + m_block;
        *(int4*)op       = *(const int4*)&hbf[t][0];
        *(int4*)(op + 8) = *(const int4*)&hbf[t][8];
    }
    // es/ed in fp32: thread (m = t>>4, sg = t&15), partial over i = sg*8..+7
    {
        int m = t >> 4, sg = t & 15;
        const float* xp = x + (size_t)(m0g + m) * FF + sg * 8;
        float4 x0 = *(const float4*)xp;
        float4 x1 = *(const float4*)(xp + 4);
#pragma unroll
        for (int hd = 0; hd < 4; ++hd) {
            const float* vsp = &vs_s[hd][sg * 8];
            const float* vdp = &vd_s[hd][sg * 8];
            float es = x0.x * vsp[0] + x0.y * vsp[1] + x0.z * vsp[2] + x0.w * vsp[3]
                     + x1.x * vsp[4] + x1.y * vsp[5] + x1.z * vsp[6] + x1.w * vsp[7];
            float ed = x0.x * vdp[0] + x0.y * vdp[1] + x0.z * vdp[2] + x0.w * vdp[3]
                     + x1.x * vdp[4] + x1.y * vdp[5] + x1.z * vdp[6] + x1.w * vdp[7];
#pragma unroll
            for (int k = 1; k < 16; k <<= 1) {
                es += __shfl_xor(es, k);
                ed += __shfl_xor(ed, k);
            }
            if (sg == 0) {
                size_t eb = (size_t)(b * HH + hd) * NN + m_block + m;
                es_t[eb] = es * LOG2E;
                ed_t[eb] = ed * LOG2E;
            }
        }
    }
}

// ---------------- K2 (v3): fused masked-softmax attention + PV via MFMA.
// RESTRUCTURED vs R1 baseline:
//  - NO ht LDS staging: B-fragments (short8) read directly from global.
//    Each wave reads its ht rows exactly once (no intra-wave reuse) and the
//    128 KB (b,h)-slice is L2-resident across the 32 x-blocks -> staging
//    through LDS was a pure round-trip + full-block barrier cost.
//  - 512-thr blocks (8 waves = 4 n-groups x 2 K-halves), grid (32,16).
//    LDS 144.5 KB -> 16 KB (ep pairs, aliased as reduction scratch), bits
//    loaded in-loop (not 32 VGPRs upfront) -> multiple independent
//    blocks/CU instead of one barrier-lockstep 16-wave block.
//  - ep scheme reverted to R1's precomputed exp-pair table (exp2 OUT of the
//    inner loop; R2 proved in-loop TRANS costs ~1:1 in wall time).
// Weight math identical to R1 -> bit-identical output expected.
__global__ __launch_bounds__(512) void k_attn(
        const unsigned short* __restrict__ ht,
        const unsigned int* __restrict__ bits,
        const float* __restrict__ es_t,
        const float* __restrict__ ed_t,
        float* __restrict__ out) {
    __shared__ float ep[NN * 2];   // 16 KB: (Ed_p, Ed_n) per m; reused as scratch
    int t = threadIdx.x;
    int n0 = blockIdx.x * 64;
    int bh = blockIdx.y;
    int b = bh >> 2, head = bh & 3;

    int wid = t >> 6, lane = t & 63;
    int q = lane >> 4, r = lane & 15;
    int qo = q * 8;
    int half = wid >> 2, wsub = wid & 3;
    int n_l = wsub * 16 + r;

    // stage (Ed_p, Ed_n) pairs: 4 m per thread
    {
        float4 v = ((const float4*)(ed_t + (size_t)bh * NN))[t];
        float4 o01, o23;
        o01.x = exp2_fast(v.x); o01.y = exp2_fast(NEG_SLOPE * v.x);
        o01.z = exp2_fast(v.y); o01.w = exp2_fast(NEG_SLOPE * v.y);
        o23.x = exp2_fast(v.z); o23.y = exp2_fast(NEG_SLOPE * v.z);
        o23.z = exp2_fast(v.w); o23.w = exp2_fast(NEG_SLOPE * v.w);
        ((float4*)ep)[2 * t]     = o01;
        ((float4*)ep)[2 * t + 1] = o23;
    }
    float esv = es_t[(size_t)bh * NN + n0 + n_l];
    floatx2 es2 = {exp2_fast(esv), exp2_fast(NEG_SLOPE * esv)};
    __syncthreads();

    floatx4 acc0 = {0.f, 0.f, 0.f, 0.f};
    floatx4 acc1 = {0.f, 0.f, 0.f, 0.f};
    floatx4 accd = {0.f, 0.f, 0.f, 0.f};
    union { short8 s8; int i[4]; } ones;
    ones.i[0] = 0x3F803F80; ones.i[1] = 0x3F803F80;
    ones.i[2] = 0x3F803F80; ones.i[3] = 0x3F803F80;

    const float* eph = ep + half * 2048;   // pairs for this K-half
    const unsigned short* hrow0 = ht + (size_t)bh * DD * NN
                                  + (size_t)r * NN + half * 1024 + qo;
    const unsigned short* hrow1 = hrow0 + 16 * NN;
    const unsigned int* bp = bits + (size_t)(n0 + n_l) * 64 + half * 32;

#pragma unroll
    for (int g = 0; g < 8; ++g) {
        int4 bwv = *(const int4*)(bp + g * 4);
#pragma unroll
        for (int c = 0; c < 4; ++c) {
            unsigned int word = (unsigned int)((&bwv.x)[c]);
            int mb = (g * 4 + c) * 32;
            unsigned int wq = word >> qo;
            const float* pbase = eph + (mb + qo) * 2;
            union { short8 s8; int i[4]; } af;
#pragma unroll
            for (int jp = 0; jp < 4; ++jp) {
                float4 d2 = *(const float4*)(pbase + jp * 4);
                floatx2 p0 = es2 * (floatx2){d2.x, d2.y};
                floatx2 p1 = es2 * (floatx2){d2.z, d2.w};
                float w0 = fmaxf(p0.x, p0.y);
                float w1 = fmaxf(p1.x, p1.y);
                int m0 = bit_mask(wq, 2 * jp);
                int m1 = bit_mask(wq, 2 * jp + 1);
                w0 = __uint_as_float(__float_as_uint(w0) & (unsigned int)m0);
                w1 = __uint_as_float(__float_as_uint(w1) & (unsigned int)m1);
                af.i[jp] = __builtin_amdgcn_perm(__float_as_uint(w1),
                                                 __float_as_uint(w0),
                                                 0x07060302u);
            }
            short8 b0 = *(const short8*)(hrow0 + mb);   // global, L2-resident
            short8 b1 = *(const short8*)(hrow1 + mb);
            acc0 = __builtin_amdgcn_mfma_f32_16x16x32_bf16(af.s8, b0, acc0, 0, 0, 0);
            acc1 = __builtin_amdgcn_mfma_f32_16x16x32_bf16(af.s8, b1, acc1, 0, 0, 0);
            accd = __builtin_amdgcn_mfma_f32_16x16x32_bf16(af.s8, ones.s8, accd, 0, 0, 0);
        }
    }

    // K-half pair reduction through LDS (alias ep as fp32 scratch; 12 KB)
    __syncthreads();
    float* scr = ep;
    if (half == 1) {
        int base = (wsub * 64 + lane) * 12;
        *(floatx4*)&scr[base + 0] = acc0;
        *(floatx4*)&scr[base + 4] = acc1;
        *(floatx4*)&scr[base + 8] = accd;
    }
    __syncthreads();
    if (half == 0) {
        int base = (wsub * 64 + lane) * 12;
        floatx4 p0 = *(const floatx4*)&scr[base + 0];
        floatx4 p1 = *(const floatx4*)&scr[base + 4];
        floatx4 pd = *(const floatx4*)&scr[base + 8];
#pragma unroll
        for (int k = 0; k < 4; ++k) {
            acc0[k] += p0[k]; acc1[k] += p1[k]; accd[k] += pd[k];
        }
        // C/D layout: col = lane&15 (= r), row = q*4 + reg
#pragma unroll
        for (int reg = 0; reg < 4; ++reg) {
            int nrow = n0 + wsub * 16 + q * 4 + reg;
            float inv = 1.0f / accd[reg];
            float* op = out + ((size_t)(b * NN + nrow)) * FF + head * DD;
            op[r]      = acc0[reg] * inv;
            op[16 + r] = acc1[reg] * inv;
        }
    }
}

extern "C" void kernel_launch(void* const* d_in, const int* in_sizes, int n_in,
                              void* d_out, int out_size, void* d_ws, size_t ws_size,
                              hipStream_t stream) {
    const float* x     = (const float*)d_in[0];
    const int*   adj   = (const int*)d_in[1];
    const float* W     = (const float*)d_in[2];
    const float* a_src = (const float*)d_in[3];
    const float* a_dst = (const float*)d_in[4];
    float* out = (float*)d_out;

    float* es_t = (float*)d_ws;                                // 32,768 f
    float* ed_t = es_t + (size_t)BB * HH * NN;                 // 32,768 f
    unsigned int* bits = (unsigned int*)(ed_t + (size_t)BB * HH * NN);     // 131,072 u32
    unsigned short* ht = (unsigned short*)(bits + (size_t)NN * (NN / 32)); // 2,097,152 bf16

    hipLaunchKernelGGL(k_prep, dim3(1024), dim3(256), 0, stream,
                       x, W, a_src, a_dst, adj, ht, es_t, ed_t, bits);
    hipLaunchKernelGGL(k_attn, dim3(NN / 64, BB * HH), dim3(512), 0, stream,
                       ht, bits, es_t, ed_t, out);
}

// Round 4
// 101.350 us; speedup vs baseline: 1.1369x; 1.1369x over previous
//
#include <hip/hip_runtime.h>
#include <math.h>

#define BB 4
#define NN 2048
#define FF 128
#define HH 4
#define DD 32
#define NEG_SLOPE 0.2f
#define LOG2E 1.4426950408889634f

typedef __attribute__((ext_vector_type(8))) short short8;
typedef __attribute__((ext_vector_type(4))) float floatx4;
typedef __attribute__((ext_vector_type(2))) float floatx2;

__device__ __forceinline__ float exp2_fast(float x) {
#if __has_builtin(__builtin_amdgcn_exp2f)
    return __builtin_amdgcn_exp2f(x);
#else
    return exp2f(x);
#endif
}

__device__ __forceinline__ int bit_mask(unsigned int w, int bit) {
#if __has_builtin(__builtin_amdgcn_sbfe)
    return __builtin_amdgcn_sbfe((int)w, bit, 1);    // v_bfe_i32: 0 or -1
#else
    return ((int)(w << (31 - bit))) >> 31;
#endif
}

// pack two fp32 -> one u32 holding (bf16(hi)<<16 | bf16(lo)), RTNE
__device__ __forceinline__ unsigned int pack2_rtne(float lo, float hi) {
    unsigned int ul = __float_as_uint(lo); ul += 0x7FFFu + ((ul >> 16) & 1u);
    unsigned int uh = __float_as_uint(hi); uh += 0x7FFFu + ((uh >> 16) & 1u);
    return (ul >> 16) | (uh & 0xFFFF0000u);
}

// ---------------- K1: prep = {MFMA gemm_fused (blocks 0..511), pack_adj (512..1023)}
// (unchanged from verified baseline)
__global__ __launch_bounds__(256) void k_prep(const float* __restrict__ x,
                                              const float* __restrict__ W,
                                              const float* __restrict__ a_src,
                                              const float* __restrict__ a_dst,
                                              const int* __restrict__ adj,
                                              unsigned short* __restrict__ ht,
                                              float* __restrict__ es_t,
                                              float* __restrict__ ed_t,
                                              unsigned int* __restrict__ bits) {
    __shared__ unsigned short wbf[128][144];   // 36.9 KB, W as bf16 [o][i]
    __shared__ unsigned short hbf[128][24];    // 6 KB, h^T as bf16 [o][m_local]
    __shared__ float vs_s[HH][FF], vd_s[HH][FF];   // 4 KB
    __shared__ float as_s[FF], ad_s[FF];           // 1 KB
    int t = threadIdx.x;

    if (blockIdx.x >= 512) {
        // ---- pack_adj ----
        int idx = (blockIdx.x - 512) * 256 + t;
        int n = idx >> 6, w = idx & 63;
        const int4* base = (const int4*)(adj + (size_t)n * NN + w * 32);
        unsigned int word = 0;
#pragma unroll
        for (int q = 0; q < 8; ++q) {
            int4 a = base[q];
            word |= ((unsigned int)(a.x & 1)) << (q * 4 + 0);
            word |= ((unsigned int)(a.y & 1)) << (q * 4 + 1);
            word |= ((unsigned int)(a.z & 1)) << (q * 4 + 2);
            word |= ((unsigned int)(a.w & 1)) << (q * 4 + 3);
        }
        bits[idx] = word;
        return;
    }

    int m0g = blockIdx.x * 16;
    int b = m0g >> 11;
    int m_block = m0g & 2047;

    if (t < FF) { as_s[t] = a_src[t]; ad_s[t] = a_dst[t]; }
    // stage W -> bf16 LDS: 2048 chunks of 8 shorts
#pragma unroll
    for (int k = 0; k < 8; ++k) {
        int idx = t + k * 256;
        int row = idx >> 4, ch = idx & 15;           // 16 chunks of 8 per row
        const float* wp = W + (size_t)row * FF + ch * 8;
        float4 v0 = *(const float4*)wp;
        float4 v1 = *(const float4*)(wp + 4);
        unsigned int u[4];
        u[0] = pack2_rtne(v0.x, v0.y); u[1] = pack2_rtne(v0.z, v0.w);
        u[2] = pack2_rtne(v1.x, v1.y); u[3] = pack2_rtne(v1.z, v1.w);
        *(int4*)&wbf[row][ch * 8] = *(const int4*)u;
    }
    __syncthreads();

    // per-head column sums: vs[h][i] = sum_d W[h*32+d][i]*a_src[h][d]
    {
        int i = t & 127;
        float acc4[4] = {0.f, 0.f, 0.f, 0.f};
        if (t < 128) {
            for (int o = 0; o < 128; ++o) {
                float wv = __uint_as_float(((unsigned int)wbf[o][i]) << 16);
                acc4[o >> 5] += wv * as_s[o];
            }
#pragma unroll
            for (int hd = 0; hd < 4; ++hd) vs_s[hd][i] = acc4[hd];
        } else {
            for (int o = 0; o < 128; ++o) {
                float wv = __uint_as_float(((unsigned int)wbf[o][i]) << 16);
                acc4[o >> 5] += wv * ad_s[o];
            }
#pragma unroll
            for (int hd = 0; hd < 4; ++hd) vd_s[hd][i] = acc4[hd];
        }
    }

    // MFMA: h[m0g..+15][0..127] ; wave wid does col-tiles c=wid*2, wid*2+1
    int wid = t >> 6, lane = t & 63;
    int r = lane & 15, q = lane >> 4;
    floatx4 acc[2] = {{0.f,0.f,0.f,0.f},{0.f,0.f,0.f,0.f}};
    const float* xrow = x + (size_t)(m0g + r) * FF + q * 8;
#pragma unroll
    for (int kk = 0; kk < 4; ++kk) {
        float4 a0 = *(const float4*)(xrow + kk * 32);
        float4 a1 = *(const float4*)(xrow + kk * 32 + 4);
        union { short8 s8; unsigned int u[4]; } af;
        af.u[0] = pack2_rtne(a0.x, a0.y); af.u[1] = pack2_rtne(a0.z, a0.w);
        af.u[2] = pack2_rtne(a1.x, a1.y); af.u[3] = pack2_rtne(a1.z, a1.w);
#pragma unroll
        for (int c = 0; c < 2; ++c) {
            int o = (wid * 2 + c) * 16 + r;          // B col = lane&15
            short8 bf = *(const short8*)&wbf[o][kk * 32 + q * 8];
            acc[c] = __builtin_amdgcn_mfma_f32_16x16x32_bf16(af.s8, bf, acc[c], 0, 0, 0);
        }
    }
    // store h^T (bf16) to LDS: lane holds col o, rows q*4+reg
#pragma unroll
    for (int c = 0; c < 2; ++c) {
        int o = (wid * 2 + c) * 16 + r;
        unsigned int u2[2];
        u2[0] = pack2_rtne(acc[c][0], acc[c][1]);
        u2[1] = pack2_rtne(acc[c][2], acc[c][3]);
        *(int2*)&hbf[o][q * 4] = *(const int2*)u2;
    }
    __syncthreads();

    // ht write: thread t<128 handles col o=t -> ht[b*4+hd][d][m_block..+15]
    if (t < 128) {
        int hd = t >> 5, d = t & 31;
        unsigned short* op = ht + ((size_t)(b * HH + hd) * DD + d) * NN + m_block;
        *(int4*)op       = *(const int4*)&hbf[t][0];
        *(int4*)(op + 8) = *(const int4*)&hbf[t][8];
    }
    // es/ed in fp32: thread (m = t>>4, sg = t&15), partial over i = sg*8..+7
    {
        int m = t >> 4, sg = t & 15;
        const float* xp = x + (size_t)(m0g + m) * FF + sg * 8;
        float4 x0 = *(const float4*)xp;
        float4 x1 = *(const float4*)(xp + 4);
#pragma unroll
        for (int hd = 0; hd < 4; ++hd) {
            const float* vsp = &vs_s[hd][sg * 8];
            const float* vdp = &vd_s[hd][sg * 8];
            float es = x0.x * vsp[0] + x0.y * vsp[1] + x0.z * vsp[2] + x0.w * vsp[3]
                     + x1.x * vsp[4] + x1.y * vsp[5] + x1.z * vsp[6] + x1.w * vsp[7];
            float ed = x0.x * vdp[0] + x0.y * vdp[1] + x0.z * vdp[2] + x0.w * vdp[3]
                     + x1.x * vdp[4] + x1.y * vdp[5] + x1.z * vdp[6] + x1.w * vdp[7];
#pragma unroll
            for (int k = 1; k < 16; k <<= 1) {
                es += __shfl_xor(es, k);
                ed += __shfl_xor(ed, k);
            }
            if (sg == 0) {
                size_t eb = (size_t)(b * HH + hd) * NN + m_block + m;
                es_t[eb] = es * LOG2E;
                ed_t[eb] = ed * LOG2E;
            }
        }
    }
}

// ---------------- K2 (v4): R1 structure VERBATIM (16 waves, LDS-staged hb,
// K-split halves) with ONE algebraic change: the per-row factor
// es_p = exp2(esv) cancels between numerator and denominator (softmax is
// scale-invariant per row), so the A-fragment weight becomes
//   w~[n][m] = max(Ed_p[m], tn * Ed_n[m]),  tn = exp2(-0.8*esv)
// (was max(es_p*Ed_p, es_n*Ed_n)): 4 VALU/jp instead of 6, -8 VALU/c-iter,
// and the es2 pair is replaced by one scalar tn.
#define HTS 2056
__global__ __launch_bounds__(1024) void k_attn(
        const unsigned short* __restrict__ ht,
        const unsigned int* __restrict__ bits,
        const float* __restrict__ es_t,
        const float* __restrict__ ed_t,
        float* __restrict__ out) {
    __shared__ unsigned short hb[DD * HTS];   // 128.5 KB
    __shared__ float ep[NN * 2];               // 16 KB: (Ed_p, Ed_n) per m
    int t = threadIdx.x;
    int n0 = blockIdx.x * 128;
    int bh = blockIdx.y;
    int b = bh >> 2, head = bh & 3;

    int wid = t >> 6, lane = t & 63;
    int q = lane >> 4, r = lane & 15;
    int qo = q * 8;
    int half = wid >> 3, wsub = wid & 7;
    int n_l = wsub * 16 + r;

    // stage (Ed_p, Ed_n) pairs: 2 m per thread
    {
        float2 v = ((const float2*)(ed_t + (size_t)bh * NN))[t];
        float4 o;
        o.x = exp2_fast(v.x); o.y = exp2_fast(NEG_SLOPE * v.x);
        o.z = exp2_fast(v.y); o.w = exp2_fast(NEG_SLOPE * v.y);
        ((float4*)ep)[t] = o;
    }
    // stage full ht slice: 8192 int4 chunks
    {
        const unsigned short* htp = ht + (size_t)bh * DD * NN;
#pragma unroll
        for (int k = 0; k < 8; ++k) {
            int qq = t + k * 1024;
            int d = qq >> 8, cm = qq & 255;
            int4 v = *(const int4*)(htp + (size_t)d * NN + cm * 8);
            *(int4*)&hb[d * HTS + cm * 8] = v;
        }
    }
    // adjacency bits for this lane's row + K-half: 32 words in registers
    int4 bw[8];
    {
        const int4* bp = (const int4*)(bits + (size_t)(n0 + n_l) * 64 + half * 32);
#pragma unroll
        for (int g = 0; g < 8; ++g) bw[g] = bp[g];
    }
    float esv = es_t[(size_t)bh * NN + n0 + n_l];   // already * log2e
    float tn = exp2_fast(-0.8f * esv);              // es_n/es_p, row-constant
    __syncthreads();

    floatx4 acc0 = {0.f, 0.f, 0.f, 0.f};
    floatx4 acc1 = {0.f, 0.f, 0.f, 0.f};
    floatx4 accd = {0.f, 0.f, 0.f, 0.f};
    union { short8 s8; int i[4]; } ones;
    ones.i[0] = 0x3F803F80; ones.i[1] = 0x3F803F80;
    ones.i[2] = 0x3F803F80; ones.i[3] = 0x3F803F80;

    const float* eph = ep + half * 2048;
    const unsigned short* hrow0 = &hb[r * HTS + half * 1024 + qo];
    const unsigned short* hrow1 = hrow0 + 16 * HTS;

#pragma unroll
    for (int g = 0; g < 8; ++g) {
#pragma unroll
        for (int c = 0; c < 4; ++c) {
            unsigned int word = (unsigned int)((&bw[g].x)[c]);
            int mb = (g * 4 + c) * 32;
            unsigned int wq = word >> qo;
            const float* pbase = eph + (mb + qo) * 2;
            union { short8 s8; int i[4]; } af;
#pragma unroll
            for (int jp = 0; jp < 4; ++jp) {
                float4 d2 = *(const float4*)(pbase + jp * 4);
                float w0 = fmaxf(d2.x, tn * d2.y);
                float w1 = fmaxf(d2.z, tn * d2.w);
                int m0 = bit_mask(wq, 2 * jp);
                int m1 = bit_mask(wq, 2 * jp + 1);
                w0 = __uint_as_float(__float_as_uint(w0) & (unsigned int)m0);
                w1 = __uint_as_float(__float_as_uint(w1) & (unsigned int)m1);
                af.i[jp] = __builtin_amdgcn_perm(__float_as_uint(w1),
                                                 __float_as_uint(w0),
                                                 0x07060302u);
            }
            short8 b0 = *(const short8*)(hrow0 + mb);
            short8 b1 = *(const short8*)(hrow1 + mb);
            acc0 = __builtin_amdgcn_mfma_f32_16x16x32_bf16(af.s8, b0, acc0, 0, 0, 0);
            acc1 = __builtin_amdgcn_mfma_f32_16x16x32_bf16(af.s8, b1, acc1, 0, 0, 0);
            accd = __builtin_amdgcn_mfma_f32_16x16x32_bf16(af.s8, ones.s8, accd, 0, 0, 0);
        }
    }

    // K-half pair reduction through LDS (reuse hb as fp32 scratch)
    __syncthreads();
    float* scr = (float*)hb;
    if (wid >= 8) {
        int base = ((wid - 8) * 64 + lane) * 12;
        *(floatx4*)&scr[base + 0] = acc0;
        *(floatx4*)&scr[base + 4] = acc1;
        *(floatx4*)&scr[base + 8] = accd;
    }
    __syncthreads();
    if (wid < 8) {
        int base = (wid * 64 + lane) * 12;
        floatx4 p0 = *(const floatx4*)&scr[base + 0];
        floatx4 p1 = *(const floatx4*)&scr[base + 4];
        floatx4 pd = *(const floatx4*)&scr[base + 8];
#pragma unroll
        for (int k = 0; k < 4; ++k) {
            acc0[k] += p0[k]; acc1[k] += p1[k]; accd[k] += pd[k];
        }
        // C/D layout: col = lane&15 (= r), row = q*4 + reg
#pragma unroll
        for (int reg = 0; reg < 4; ++reg) {
            int nrow = n0 + wsub * 16 + q * 4 + reg;
            float inv = 1.0f / accd[reg];
            float* op = out + ((size_t)(b * NN + nrow)) * FF + head * DD;
            op[r]      = acc0[reg] * inv;
            op[16 + r] = acc1[reg] * inv;
        }
    }
}

extern "C" void kernel_launch(void* const* d_in, const int* in_sizes, int n_in,
                              void* d_out, int out_size, void* d_ws, size_t ws_size,
                              hipStream_t stream) {
    const float* x     = (const float*)d_in[0];
    const int*   adj   = (const int*)d_in[1];
    const float* W     = (const float*)d_in[2];
    const float* a_src = (const float*)d_in[3];
    const float* a_dst = (const float*)d_in[4];
    float* out = (float*)d_out;

    float* es_t = (float*)d_ws;                                // 32,768 f
    float* ed_t = es_t + (size_t)BB * HH * NN;                 // 32,768 f
    unsigned int* bits = (unsigned int*)(ed_t + (size_t)BB * HH * NN);     // 131,072 u32
    unsigned short* ht = (unsigned short*)(bits + (size_t)NN * (NN / 32)); // 2,097,152 bf16

    hipLaunchKernelGGL(k_prep, dim3(1024), dim3(256), 0, stream,
                       x, W, a_src, a_dst, adj, ht, es_t, ed_t, bits);
    hipLaunchKernelGGL(k_attn, dim3(NN / 128, BB * HH), dim3(1024), 0, stream,
                       ht, bits, es_t, ed_t, out);
}

// Round 5
// 98.268 us; speedup vs baseline: 1.1726x; 1.0314x over previous
//
#include <hip/hip_runtime.h>
#include <math.h>

#define BB 4
#define NN 2048
#define FF 128
#define HH 4
#define DD 32
#define NEG_SLOPE 0.2f
#define LOG2E 1.4426950408889634f

typedef __attribute__((ext_vector_type(8))) short short8;
typedef __attribute__((ext_vector_type(4))) float floatx4;
typedef __attribute__((ext_vector_type(2))) float floatx2;

__device__ __forceinline__ float exp2_fast(float x) {
#if __has_builtin(__builtin_amdgcn_exp2f)
    return __builtin_amdgcn_exp2f(x);
#else
    return exp2f(x);
#endif
}

__device__ __forceinline__ int bit_mask(unsigned int w, int bit) {
#if __has_builtin(__builtin_amdgcn_sbfe)
    return __builtin_amdgcn_sbfe((int)w, bit, 1);    // v_bfe_i32: 0 or -1
#else
    return ((int)(w << (31 - bit))) >> 31;
#endif
}

// pack two fp32 -> one u32 holding (bf16(hi)<<16 | bf16(lo)), RTNE
__device__ __forceinline__ unsigned int pack2_rtne(float lo, float hi) {
    unsigned int ul = __float_as_uint(lo); ul += 0x7FFFu + ((ul >> 16) & 1u);
    unsigned int uh = __float_as_uint(hi); uh += 0x7FFFu + ((uh >> 16) & 1u);
    return (ul >> 16) | (uh & 0xFFFF0000u);
}

// ---------------- K1: prep = {MFMA gemm_fused (blocks 0..511), pack_adj (512..1023)}
// Only change vs verified baseline: ed_t now stores PRECOMPUTED exp-pairs
// (exp2(ed*log2e), exp2(0.2*ed*log2e)) as float2 so k_attn's prologue is a
// plain copy (blocks are 2x as many in v5; avoid redundant exp2 there).
__global__ __launch_bounds__(256) void k_prep(const float* __restrict__ x,
                                              const float* __restrict__ W,
                                              const float* __restrict__ a_src,
                                              const float* __restrict__ a_dst,
                                              const int* __restrict__ adj,
                                              unsigned short* __restrict__ ht,
                                              float* __restrict__ es_t,
                                              float* __restrict__ ed_t,
                                              unsigned int* __restrict__ bits) {
    __shared__ unsigned short wbf[128][144];   // 36.9 KB, W as bf16 [o][i]
    __shared__ unsigned short hbf[128][24];    // 6 KB, h^T as bf16 [o][m_local]
    __shared__ float vs_s[HH][FF], vd_s[HH][FF];   // 4 KB
    __shared__ float as_s[FF], ad_s[FF];           // 1 KB
    int t = threadIdx.x;

    if (blockIdx.x >= 512) {
        // ---- pack_adj ----
        int idx = (blockIdx.x - 512) * 256 + t;
        int n = idx >> 6, w = idx & 63;
        const int4* base = (const int4*)(adj + (size_t)n * NN + w * 32);
        unsigned int word = 0;
#pragma unroll
        for (int q = 0; q < 8; ++q) {
            int4 a = base[q];
            word |= ((unsigned int)(a.x & 1)) << (q * 4 + 0);
            word |= ((unsigned int)(a.y & 1)) << (q * 4 + 1);
            word |= ((unsigned int)(a.z & 1)) << (q * 4 + 2);
            word |= ((unsigned int)(a.w & 1)) << (q * 4 + 3);
        }
        bits[idx] = word;
        return;
    }

    int m0g = blockIdx.x * 16;
    int b = m0g >> 11;
    int m_block = m0g & 2047;

    if (t < FF) { as_s[t] = a_src[t]; ad_s[t] = a_dst[t]; }
    // stage W -> bf16 LDS: 2048 chunks of 8 shorts
#pragma unroll
    for (int k = 0; k < 8; ++k) {
        int idx = t + k * 256;
        int row = idx >> 4, ch = idx & 15;           // 16 chunks of 8 per row
        const float* wp = W + (size_t)row * FF + ch * 8;
        float4 v0 = *(const float4*)wp;
        float4 v1 = *(const float4*)(wp + 4);
        unsigned int u[4];
        u[0] = pack2_rtne(v0.x, v0.y); u[1] = pack2_rtne(v0.z, v0.w);
        u[2] = pack2_rtne(v1.x, v1.y); u[3] = pack2_rtne(v1.z, v1.w);
        *(int4*)&wbf[row][ch * 8] = *(const int4*)u;
    }
    __syncthreads();

    // per-head column sums: vs[h][i] = sum_d W[h*32+d][i]*a_src[h][d]
    {
        int i = t & 127;
        float acc4[4] = {0.f, 0.f, 0.f, 0.f};
        if (t < 128) {
            for (int o = 0; o < 128; ++o) {
                float wv = __uint_as_float(((unsigned int)wbf[o][i]) << 16);
                acc4[o >> 5] += wv * as_s[o];
            }
#pragma unroll
            for (int hd = 0; hd < 4; ++hd) vs_s[hd][i] = acc4[hd];
        } else {
            for (int o = 0; o < 128; ++o) {
                float wv = __uint_as_float(((unsigned int)wbf[o][i]) << 16);
                acc4[o >> 5] += wv * ad_s[o];
            }
#pragma unroll
            for (int hd = 0; hd < 4; ++hd) vd_s[hd][i] = acc4[hd];
        }
    }

    // MFMA: h[m0g..+15][0..127] ; wave wid does col-tiles c=wid*2, wid*2+1
    int wid = t >> 6, lane = t & 63;
    int r = lane & 15, q = lane >> 4;
    floatx4 acc[2] = {{0.f,0.f,0.f,0.f},{0.f,0.f,0.f,0.f}};
    const float* xrow = x + (size_t)(m0g + r) * FF + q * 8;
#pragma unroll
    for (int kk = 0; kk < 4; ++kk) {
        float4 a0 = *(const float4*)(xrow + kk * 32);
        float4 a1 = *(const float4*)(xrow + kk * 32 + 4);
        union { short8 s8; unsigned int u[4]; } af;
        af.u[0] = pack2_rtne(a0.x, a0.y); af.u[1] = pack2_rtne(a0.z, a0.w);
        af.u[2] = pack2_rtne(a1.x, a1.y); af.u[3] = pack2_rtne(a1.z, a1.w);
#pragma unroll
        for (int c = 0; c < 2; ++c) {
            int o = (wid * 2 + c) * 16 + r;          // B col = lane&15
            short8 bf = *(const short8*)&wbf[o][kk * 32 + q * 8];
            acc[c] = __builtin_amdgcn_mfma_f32_16x16x32_bf16(af.s8, bf, acc[c], 0, 0, 0);
        }
    }
    // store h^T (bf16) to LDS: lane holds col o, rows q*4+reg
#pragma unroll
    for (int c = 0; c < 2; ++c) {
        int o = (wid * 2 + c) * 16 + r;
        unsigned int u2[2];
        u2[0] = pack2_rtne(acc[c][0], acc[c][1]);
        u2[1] = pack2_rtne(acc[c][2], acc[c][3]);
        *(int2*)&hbf[o][q * 4] = *(const int2*)u2;
    }
    __syncthreads();

    // ht write: thread t<128 handles col o=t -> ht[b*4+hd][d][m_block..+15]
    if (t < 128) {
        int hd = t >> 5, d = t & 31;
        unsigned short* op = ht + ((size_t)(b * HH + hd) * DD + d) * NN + m_block;
        *(int4*)op       = *(const int4*)&hbf[t][0];
        *(int4*)(op + 8) = *(const int4*)&hbf[t][8];
    }
    // es/ed in fp32: thread (m = t>>4, sg = t&15), partial over i = sg*8..+7
    {
        int m = t >> 4, sg = t & 15;
        const float* xp = x + (size_t)(m0g + m) * FF + sg * 8;
        float4 x0 = *(const float4*)xp;
        float4 x1 = *(const float4*)(xp + 4);
#pragma unroll
        for (int hd = 0; hd < 4; ++hd) {
            const float* vsp = &vs_s[hd][sg * 8];
            const float* vdp = &vd_s[hd][sg * 8];
            float es = x0.x * vsp[0] + x0.y * vsp[1] + x0.z * vsp[2] + x0.w * vsp[3]
                     + x1.x * vsp[4] + x1.y * vsp[5] + x1.z * vsp[6] + x1.w * vsp[7];
            float ed = x0.x * vdp[0] + x0.y * vdp[1] + x0.z * vdp[2] + x0.w * vdp[3]
                     + x1.x * vdp[4] + x1.y * vdp[5] + x1.z * vdp[6] + x1.w * vdp[7];
#pragma unroll
            for (int k = 1; k < 16; k <<= 1) {
                es += __shfl_xor(es, k);
                ed += __shfl_xor(ed, k);
            }
            if (sg == 0) {
                size_t eb = (size_t)(b * HH + hd) * NN + m_block + m;
                es_t[eb] = es * LOG2E;
                float ee = ed * LOG2E;
                float2 pr;
                pr.x = exp2_fast(ee);
                pr.y = exp2_fast(NEG_SLOPE * ee);
                *(float2*)(ed_t + eb * 2) = pr;
            }
        }
    }
}

// ---------------- K2 (v5): same verified inner math as R4 (tn-factored
// weights, K-half split, LDS-staged B), restructured for CO-RESIDENCY:
//  - 512 blocks x 8 waves (4 n-groups x 2 K-halves, 64 rows/block),
//    grid (32,16) -> 2 independent blocks per CU (decorrelated barriers;
//    one block's compute covers the other's staging/prologue/epilogue).
//  - hb staged in 4 chunks of (256 m per half): LDS 144.5 -> 49 KB.
//  - ep pairs precomputed in k_prep; prologue is a pure 16 KB copy.
#define HBW 528    // hb row stride in shorts (2x264; 528B*? -> 2-way banks, free)
#define HOF 264    // half-1 column offset within a row (256 data + 8 pad)
__global__ __launch_bounds__(512) void k_attn(
        const unsigned short* __restrict__ ht,
        const unsigned int* __restrict__ bits,
        const float* __restrict__ es_t,
        const float* __restrict__ ed_t,
        float* __restrict__ out) {
    __shared__ unsigned short hb[DD * HBW];   // 33,792 B (chunk of both halves)
    __shared__ float ep[NN * 2];               // 16,384 B: (Ed_p, Ed_n) pairs
    int t = threadIdx.x;
    int n0 = blockIdx.x * 64;
    int bh = blockIdx.y;
    int b = bh >> 2, head = bh & 3;

    int wid = t >> 6, lane = t & 63;
    int q = lane >> 4, r = lane & 15;
    int qo = q * 8;
    int half = wid >> 2, wsub = wid & 3;
    int n_l = wsub * 16 + r;

    const unsigned short* htp = ht + (size_t)bh * DD * NN;

    // ep copy: 1024 float4 over 512 threads (pairs precomputed in k_prep)
    {
        const float4* src = (const float4*)(ed_t + (size_t)bh * NN * 2);
        ((float4*)ep)[t]       = src[t];
        ((float4*)ep)[t + 512] = src[t + 512];
    }
    // stage chunk 0: [32 d][256 m of each half] = 2048 int4 over 512 thr
#pragma unroll
    for (int k2 = 0; k2 < 4; ++k2) {
        int j = t + k2 * 512;
        int hf = j >> 10, jj = j & 1023;
        int d = jj >> 5, c16 = jj & 31;
        int4 v = *(const int4*)(htp + (size_t)d * NN + hf * 1024 + c16 * 8);
        *(int4*)&hb[d * HBW + hf * HOF + c16 * 8] = v;
    }
    float esv = es_t[(size_t)bh * NN + n0 + n_l];   // already * log2e
    float tn = exp2_fast(-0.8f * esv);              // es_n/es_p, row-constant
    __syncthreads();

    floatx4 acc0 = {0.f, 0.f, 0.f, 0.f};
    floatx4 acc1 = {0.f, 0.f, 0.f, 0.f};
    floatx4 accd = {0.f, 0.f, 0.f, 0.f};
    union { short8 s8; int i[4]; } ones;
    ones.i[0] = 0x3F803F80; ones.i[1] = 0x3F803F80;
    ones.i[2] = 0x3F803F80; ones.i[3] = 0x3F803F80;

    const unsigned short* hrow0 = &hb[r * HBW + half * HOF + qo];
    const unsigned short* hrow1 = &hb[(r + 16) * HBW + half * HOF + qo];
    const unsigned int* bpb = bits + (size_t)(n0 + n_l) * 64 + half * 32;

    for (int ck = 0; ck < 4; ++ck) {
        int4 bw0 = *(const int4*)(bpb + ck * 8);
        int4 bw1 = *(const int4*)(bpb + ck * 8 + 4);
        const float* pb_ck = ep + (half * 1024 + ck * 256) * 2;
#pragma unroll
        for (int g = 0; g < 2; ++g) {
            int4 bwv = g ? bw1 : bw0;
#pragma unroll
            for (int c = 0; c < 4; ++c) {
                unsigned int word = (unsigned int)((&bwv.x)[c]);
                int mb = g * 128 + c * 32;           // chunk-local m offset
                unsigned int wq = word >> qo;
                const float* pbase = pb_ck + (mb + qo) * 2;
                union { short8 s8; int i[4]; } af;
#pragma unroll
                for (int jp = 0; jp < 4; ++jp) {
                    float4 d2 = *(const float4*)(pbase + jp * 4);
                    float w0 = fmaxf(d2.x, tn * d2.y);
                    float w1 = fmaxf(d2.z, tn * d2.w);
                    int m0 = bit_mask(wq, 2 * jp);
                    int m1 = bit_mask(wq, 2 * jp + 1);
                    w0 = __uint_as_float(__float_as_uint(w0) & (unsigned int)m0);
                    w1 = __uint_as_float(__float_as_uint(w1) & (unsigned int)m1);
                    af.i[jp] = __builtin_amdgcn_perm(__float_as_uint(w1),
                                                     __float_as_uint(w0),
                                                     0x07060302u);
                }
                short8 b0 = *(const short8*)(hrow0 + mb);
                short8 b1 = *(const short8*)(hrow1 + mb);
                acc0 = __builtin_amdgcn_mfma_f32_16x16x32_bf16(af.s8, b0, acc0, 0, 0, 0);
                acc1 = __builtin_amdgcn_mfma_f32_16x16x32_bf16(af.s8, b1, acc1, 0, 0, 0);
                accd = __builtin_amdgcn_mfma_f32_16x16x32_bf16(af.s8, ones.s8, accd, 0, 0, 0);
            }
        }
        __syncthreads();
        if (ck < 3) {
            int ckn = ck + 1;
#pragma unroll
            for (int k2 = 0; k2 < 4; ++k2) {
                int j = t + k2 * 512;
                int hf = j >> 10, jj = j & 1023;
                int d = jj >> 5, c16 = jj & 31;
                int4 v = *(const int4*)(htp + (size_t)d * NN + hf * 1024
                                        + ckn * 256 + c16 * 8);
                *(int4*)&hb[d * HBW + hf * HOF + c16 * 8] = v;
            }
        }
        __syncthreads();
    }

    // K-half pair reduction through LDS (alias hb as fp32 scratch; 12.3 KB)
    float* scr = (float*)hb;
    if (half == 1) {
        int base = (wsub * 64 + lane) * 12;
        *(floatx4*)&scr[base + 0] = acc0;
        *(floatx4*)&scr[base + 4] = acc1;
        *(floatx4*)&scr[base + 8] = accd;
    }
    __syncthreads();
    if (half == 0) {
        int base = (wsub * 64 + lane) * 12;
        floatx4 p0 = *(const floatx4*)&scr[base + 0];
        floatx4 p1 = *(const floatx4*)&scr[base + 4];
        floatx4 pd = *(const floatx4*)&scr[base + 8];
#pragma unroll
        for (int k = 0; k < 4; ++k) {
            acc0[k] += p0[k]; acc1[k] += p1[k]; accd[k] += pd[k];
        }
        // C/D layout: col = lane&15 (= r), row = q*4 + reg
#pragma unroll
        for (int reg = 0; reg < 4; ++reg) {
            int nrow = n0 + wsub * 16 + q * 4 + reg;
            float inv = 1.0f / accd[reg];
            float* op = out + ((size_t)(b * NN + nrow)) * FF + head * DD;
            op[r]      = acc0[reg] * inv;
            op[16 + r] = acc1[reg] * inv;
        }
    }
}

extern "C" void kernel_launch(void* const* d_in, const int* in_sizes, int n_in,
                              void* d_out, int out_size, void* d_ws, size_t ws_size,
                              hipStream_t stream) {
    const float* x     = (const float*)d_in[0];
    const int*   adj   = (const int*)d_in[1];
    const float* W     = (const float*)d_in[2];
    const float* a_src = (const float*)d_in[3];
    const float* a_dst = (const float*)d_in[4];
    float* out = (float*)d_out;

    float* es_t = (float*)d_ws;                                   // 32,768 f
    float* ed_t = es_t + (size_t)BB * HH * NN;                    // 65,536 f (pairs)
    unsigned int* bits = (unsigned int*)(ed_t + (size_t)BB * HH * NN * 2); // 131,072 u32
    unsigned short* ht = (unsigned short*)(bits + (size_t)NN * (NN / 32)); // 2,097,152 bf16

    hipLaunchKernelGGL(k_prep, dim3(1024), dim3(256), 0, stream,
                       x, W, a_src, a_dst, adj, ht, es_t, ed_t, bits);
    hipLaunchKernelGGL(k_attn, dim3(NN / 64, BB * HH), dim3(512), 0, stream,
                       ht, bits, es_t, ed_t, out);
}